// Round 6
// baseline (68.772 us; speedup 1.0000x reference)
//
#include <hip/hip_runtime.h>

// BQWarp: ball query, N=32768 queries vs G=4096 db points, radius 0.25, K=10.
// Outputs (concatenated in d_out, float32):
//   [0, N*K)       mapping (first-K in-radius db indices in index order, 0 if invalid)
//   [N*K, N*K*4)   coords  (N,K,3) gathered db coords, 0 if invalid
//
// Round 5 (resubmit; previous run died to container infra, not the kernel):
// wave-per-query ballot scan, depth-2 software pipeline.
//   - 1 query per wave (independent early exit -> no max-of-N tail coupling).
//   - Chunks processed in pairs; the next pair's 6 loads issue before the two
//     ballot bodies, so L1/L2 latency hides under compute + other waves.
//   - mbcnt_lo/hi gives each hit lane its prefix count in the ballot mask.
//   - Early-exit check once per 128 points (uniform SALU branch).
//   - __f*_rn pins the exact numpy rounding order (no FMA contraction) so the
//     d2 <= R^2 mask is bit-identical to the reference.

#define BQ_K 10
#define BQ_R2 0.0625f   // 0.25^2 exactly representable

__global__ __launch_bounds__(256, 8) void bqwarp_kernel(
    const float* __restrict__ x,      // N*3 query coords
    const float* __restrict__ db,     // G*3 db coords
    float* __restrict__ out_map,      // N*K (indices as floats)
    float* __restrict__ out_pts,      // N*K*3
    int N, int G)
{
    const int lane = threadIdx.x & 63;
    const int wave = threadIdx.x >> 6;
    const int q = blockIdx.x * 4 + wave;   // one query per wave
    if (q >= N) return;                    // wave-uniform

    const float qx = x[3 * q + 0];
    const float qy = x[3 * q + 1];
    const float qz = x[3 * q + 2];

    float* __restrict__ omap = out_map + (size_t)q * BQ_K;
    float* __restrict__ opts = out_pts + (size_t)q * BQ_K * 3;

    const int nchunk = G >> 6;             // 64 (G = 4096, multiple of 128)
    int cnt = 0;                           // uniform across the wave

    // Preload chunk pair {0,1}.
    float ax = db[3 * lane + 0];
    float ay = db[3 * lane + 1];
    float az = db[3 * lane + 2];
    float bx = db[3 * (64 + lane) + 0];
    float by = db[3 * (64 + lane) + 1];
    float bz = db[3 * (64 + lane) + 2];

    for (int c = 0; c < nchunk; c += 2) {
        // Prefetch pair {c+2, c+3} (clamped; last iter re-fetches itself).
        const int cA = (c + 2 < nchunk) ? c + 2 : c;
        const int cB = (c + 3 < nchunk) ? c + 3 : c + 1;
        const int gA = (cA << 6) | lane;
        const int gB = (cB << 6) | lane;
        const float nax = db[3 * gA + 0];
        const float nay = db[3 * gA + 1];
        const float naz = db[3 * gA + 2];
        const float nbx = db[3 * gB + 0];
        const float nby = db[3 * gB + 1];
        const float nbz = db[3 * gB + 2];

        // ---- body A (chunk c) ----
        {
            const float dx = __fsub_rn(qx, ax);
            const float dy = __fsub_rn(qy, ay);
            const float dz = __fsub_rn(qz, az);
            const float d2 = __fadd_rn(
                __fadd_rn(__fmul_rn(dx, dx), __fmul_rn(dy, dy)),
                __fmul_rn(dz, dz));
            const bool hit = (d2 <= BQ_R2);
            const unsigned long long m = __ballot(hit);
            if (hit) {
                const int prefix = __builtin_amdgcn_mbcnt_hi(
                    (unsigned)(m >> 32),
                    __builtin_amdgcn_mbcnt_lo((unsigned)m, 0u));
                const int slot = cnt + prefix;
                if (slot < BQ_K) {
                    omap[slot] = (float)((c << 6) | lane);
                    opts[3 * slot + 0] = ax;
                    opts[3 * slot + 1] = ay;
                    opts[3 * slot + 2] = az;
                }
            }
            cnt += __popcll(m);
        }

        // ---- body B (chunk c+1) ----
        {
            const float dx = __fsub_rn(qx, bx);
            const float dy = __fsub_rn(qy, by);
            const float dz = __fsub_rn(qz, bz);
            const float d2 = __fadd_rn(
                __fadd_rn(__fmul_rn(dx, dx), __fmul_rn(dy, dy)),
                __fmul_rn(dz, dz));
            const bool hit = (d2 <= BQ_R2);
            const unsigned long long m = __ballot(hit);
            if (hit) {
                const int prefix = __builtin_amdgcn_mbcnt_hi(
                    (unsigned)(m >> 32),
                    __builtin_amdgcn_mbcnt_lo((unsigned)m, 0u));
                const int slot = cnt + prefix;
                if (slot < BQ_K) {
                    omap[slot] = (float)(((c + 1) << 6) | lane);
                    opts[3 * slot + 0] = bx;
                    opts[3 * slot + 1] = by;
                    opts[3 * slot + 2] = bz;
                }
            }
            cnt += __popcll(m);
        }

        if (cnt >= BQ_K) break;            // uniform, once per 128 points

        ax = nax; ay = nay; az = naz;
        bx = nbx; by = nby; bz = nbz;
    }

    // Parallel zero-fill of unused slots (d_out is poisoned before each launch).
    const int c0 = cnt < BQ_K ? cnt : BQ_K;
    if (lane >= c0 && lane < BQ_K) {
        omap[lane] = 0.0f;
        opts[3 * lane + 0] = 0.0f;
        opts[3 * lane + 1] = 0.0f;
        opts[3 * lane + 2] = 0.0f;
    }
}

extern "C" void kernel_launch(void* const* d_in, const int* in_sizes, int n_in,
                              void* d_out, int out_size, void* d_ws, size_t ws_size,
                              hipStream_t stream) {
    const float* x  = (const float*)d_in[0];   // (1, 32768, 3) float32
    const float* pg = (const float*)d_in[1];   // (1, 32, 16, 8, 3) float32

    const int N = in_sizes[0] / 3;   // 32768
    const int G = in_sizes[1] / 3;   // 4096

    float* out_map = (float*)d_out;                 // N*K floats
    float* out_pts = out_map + (size_t)N * BQ_K;    // N*K*3 floats

    const int block = 256;                          // 4 waves = 4 queries/block
    const int nblk = (N + 3) / 4;                   // 8192 blocks
    bqwarp_kernel<<<nblk, block, 0, stream>>>(x, pg, out_map, out_pts, N, G);
}